// Round 5
// baseline (163.147 us; speedup 1.0000x reference)
//
#include <hip/hip_runtime.h>

typedef __bf16 bf16_t;
typedef bf16_t bf16x8 __attribute__((ext_vector_type(8)));
typedef bf16_t bf16x4 __attribute__((ext_vector_type(4)));
typedef float f32x4 __attribute__((ext_vector_type(4)));

__device__ __forceinline__ f32x4 mfma16(bf16x8 a, bf16x8 b, f32x4 c) {
  return __builtin_amdgcn_mfma_f32_16x16x32_bf16(a, b, c, 0, 0, 0);
}

__device__ __forceinline__ void gload16(const bf16_t* g, bf16_t* l) {
  __builtin_amdgcn_global_load_lds(
      (const __attribute__((address_space(1))) void*)g,
      (__attribute__((address_space(3))) void*)l, 16, 0, 0);
}

#define BARRIER()                      \
  do {                                 \
    asm volatile("" ::: "memory");     \
    __builtin_amdgcn_s_barrier();      \
    asm volatile("" ::: "memory");     \
  } while (0)
#define VMCNT(n) asm volatile("s_waitcnt vmcnt(" #n ")" ::: "memory")

// ------- merged prep: x f32->bf16 convert + both weight transposes -------
__global__ void prep_kernel(const float* __restrict__ x, const float* __restrict__ wq,
                            const float* __restrict__ wp, bf16_t* __restrict__ xb,
                            bf16_t* __restrict__ wqt, bf16_t* __restrict__ wpt) {
  __shared__ bf16_t tile[32][33];
  const int bid = blockIdx.x;
  if (bid < 12288) {
    int i = bid * 256 + threadIdx.x;
    float4 v = ((const float4*)x)[i];
    bf16x4 o;
    o[0] = (bf16_t)v.x; o[1] = (bf16_t)v.y; o[2] = (bf16_t)v.z; o[3] = (bf16_t)v.w;
    *(bf16x4*)&xb[(size_t)i * 4] = o;
    return;
  }
  const int t = bid - 12288;
  const int ty = t / 96, txb = t % 96;
  const float* in;
  bf16_t* out;
  int N, n0;
  if (txb < 72) { in = wq; out = wqt; N = 2304; n0 = txb * 32; }
  else          { in = wp; out = wpt; N = 768;  n0 = (txb - 72) * 32; }
  const int k0 = ty * 32;
  const int tx = threadIdx.x & 31, tyy = threadIdx.x >> 5;
#pragma unroll
  for (int ph = 0; ph < 4; ++ph) {
    int k = tyy + ph * 8;
    tile[k][tx] = (bf16_t)in[(size_t)(k0 + k) * N + n0 + tx];
  }
  __syncthreads();
#pragma unroll
  for (int ph = 0; ph < 4; ++ph) {
    int n = tyy + ph * 8;
    out[(size_t)(n0 + n) * 768 + k0 + tx] = tile[tx][n];
  }
}

// ------- persistent 128xBN bf16 GEMM, dbuf + counted vmcnt (T4) -------
// C = A[M][768] * Bt[N][768]^T. 4 waves (2x2). Per K-step:
//   BARRIER -> stage(s+1)->buf^1 -> VMCNT(LOADS) -> BARRIER -> compute(s)<-buf
// VMCNT(0) only at the last tile of the last job. Stage index s runs
// continuously across jobs so next-job prefetch falls out of the schedule.
template <int BN, int MAXB, bool F32OUT>
__global__ __launch_bounds__(256, MAXB) void gemm_cnt(
    const bf16_t* __restrict__ A, const bf16_t* __restrict__ Bt,
    void* __restrict__ Cout, int N, int nbn, int q, int r) {
  constexpr int K = 768;
  constexpr int NKT = 12;          // K / 64
  constexpr int NQ = BN / 32;      // B n-quadrants per wave (and B loads/thread)
  __shared__ bf16_t As[2][128 * 64];
  __shared__ bf16_t Bs[2][BN * 64];
  const int tid = threadIdx.x;
  const int lane = tid & 63;
  const int w = tid >> 6;
  const int wm = w >> 1, wn = w & 1;
  const int lr = lane & 15, kg = lane >> 4;

  // XCD-chunked remap
  const int G = gridDim.x;
  const int bid = blockIdx.x;
  const int lb = (bid & 7) * (G >> 3) + (bid >> 3);
  int nj, start;
  if (lb < r) { nj = q + 1; start = lb * (q + 1); }
  else        { nj = q;     start = r * (q + 1) + (lb - r) * q; }
  const int S = nj * NKT;

  const int sr = tid >> 3, sslot = tid & 7;

  auto stageS = [&](int s) {
    if (s >= S) return;
    const int jb = s / NKT;
    const int kt = s - jb * NKT;
    const int job = start + jb;
    const int bm = job / nbn, bn = job - bm * nbn;
    const bf16_t* Aj = A + (size_t)bm * (128 * K);
    const bf16_t* Bj = Bt + (size_t)bn * (BN * K);
    const int k0 = kt << 6;
    const int buf = s & 1;
#pragma unroll
    for (int it = 0; it < 4; ++it) {
      int rr = it * 32 + sr;
      gload16(Aj + (size_t)rr * K + (k0 + ((sslot ^ (rr & 7)) << 3)),
              &As[buf][(it * 256 + tid) * 8]);
    }
#pragma unroll
    for (int it = 0; it < NQ; ++it) {
      int rr = it * 32 + sr;
      gload16(Bj + (size_t)rr * K + (k0 + ((sslot ^ (rr & 7)) << 3)),
              &Bs[buf][(it * 256 + tid) * 8]);
    }
  };

  stageS(0);
  int s = 0;

  for (int j = 0; j < nj; ++j) {
    f32x4 acc[4][NQ];
#pragma unroll
    for (int i = 0; i < 4; ++i)
#pragma unroll
      for (int n = 0; n < NQ; ++n) acc[i][n] = (f32x4){0.f, 0.f, 0.f, 0.f};

    const int job = start + j;
    const int bm = job / nbn, bn = job - bm * nbn;

    for (int kt = 0; kt < NKT; ++kt, ++s) {
      BARRIER();        // all waves done reading buf^1 (tile s-1)
      stageS(s + 1);    // prefetch into buf^1
      if (s + 1 < S) {
        if constexpr (BN == 128) { VMCNT(8); } else { VMCNT(6); }
      } else {
        VMCNT(0);
      }
      BARRIER();        // everyone's stage(s) landed in buf
      const int buf = s & 1;
#pragma unroll
      for (int kk = 0; kk < 2; ++kk) {
        const int slot = ((kk << 2) + kg) ^ (lr & 7);
        bf16x8 af[4], bfv[NQ];
#pragma unroll
        for (int mq = 0; mq < 4; ++mq) {
          int rr = wm * 64 + mq * 16 + lr;
          af[mq] = *(const bf16x8*)&As[buf][(rr << 6) + (slot << 3)];
        }
#pragma unroll
        for (int nq = 0; nq < NQ; ++nq) {
          int rr = wn * (BN / 2) + nq * 16 + lr;
          bfv[nq] = *(const bf16x8*)&Bs[buf][(rr << 6) + (slot << 3)];
        }
#pragma unroll
        for (int mq = 0; mq < 4; ++mq)
#pragma unroll
          for (int nq = 0; nq < NQ; ++nq)
            acc[mq][nq] = mfma16(af[mq], bfv[nq], acc[mq][nq]);
      }
    }

    // epilogue (stores overlap next job's in-flight prefetch; vmcnt retires
    // in order, so later VMCNT(L) waits remain safe/conservative)
    const int row0 = bm * 128 + wm * 64 + kg * 4;
    const int col0 = bn * BN + wn * (BN / 2) + lr;
#pragma unroll
    for (int mq = 0; mq < 4; ++mq)
#pragma unroll
      for (int nq = 0; nq < NQ; ++nq)
#pragma unroll
        for (int rr = 0; rr < 4; ++rr) {
          size_t idx = (size_t)(row0 + mq * 16 + rr) * N + (col0 + nq * 16);
          if constexpr (F32OUT)
            ((float*)Cout)[idx] = acc[mq][nq][rr];
          else
            ((bf16_t*)Cout)[idx] = (bf16_t)acc[mq][nq][rr];
        }
  }
}

// ---------------- causal attention: one block per (b,h) ----------------
#define ATT_H 12
__global__ __launch_bounds__(256, 2) void attn_kernel(const bf16_t* __restrict__ qkv,
                                                      bf16_t* __restrict__ obuf) {
  __shared__ bf16_t Ks[128 * 72];
  __shared__ bf16_t Vt[64 * 136];
  __shared__ bf16_t Ps[128 * 136];
  const int tid = threadIdx.x, lane = tid & 63, w = tid >> 6;
  const int lr = lane & 15, kg = lane >> 4;
  const int bh = blockIdx.x;
  const int b = bh / ATT_H, h = bh % ATT_H;
  const size_t base = (size_t)b * 128 * 2304;
  const int hoff = h * 64;

#pragma unroll
  for (int it = 0; it < 4; ++it) {
    int idx = it * 256 + tid;
    int r = idx >> 3, slot = idx & 7;
    bf16x8 v = *(const bf16x8*)&qkv[base + (size_t)r * 2304 + 768 + hoff + slot * 8];
    *(bf16x8*)&Ks[r * 72 + slot * 8] = v;
  }
#pragma unroll 4
  for (int it = 0; it < 32; ++it) {
    int idx = it * 256 + tid;
    int t = idx >> 6, d = idx & 63;
    Vt[d * 136 + t] = qkv[base + (size_t)t * 2304 + 1536 + hoff + d];
  }
  const int qrow0 = w * 32;
  bf16x8 qf[2][2];
#pragma unroll
  for (int mt = 0; mt < 2; ++mt)
#pragma unroll
    for (int kk = 0; kk < 2; ++kk)
      qf[mt][kk] = *(const bf16x8*)&qkv[base + (size_t)(qrow0 + mt * 16 + lr) * 2304 + hoff +
                                        kk * 32 + kg * 8];
  __syncthreads();

  const int NT = 2 * w + 2;
  f32x4 acc[2][8];
#pragma unroll
  for (int mt = 0; mt < 2; ++mt)
#pragma unroll
    for (int nt = 0; nt < 8; ++nt) acc[mt][nt] = (f32x4){0.f, 0.f, 0.f, 0.f};

#pragma unroll
  for (int nt = 0; nt < 8; ++nt) {
    if (nt < NT) {
#pragma unroll
      for (int kk = 0; kk < 2; ++kk) {
        bf16x8 kf = *(const bf16x8*)&Ks[(nt * 16 + lr) * 72 + kk * 32 + kg * 8];
        acc[0][nt] = mfma16(qf[0][kk], kf, acc[0][nt]);
        acc[1][nt] = mfma16(qf[1][kk], kf, acc[1][nt]);
      }
    }
  }

#pragma unroll
  for (int mt = 0; mt < 2; ++mt) {
#pragma unroll
    for (int rr = 0; rr < 4; ++rr) {
      const int row = qrow0 + mt * 16 + kg * 4 + rr;
      float m = -1e30f;
#pragma unroll
      for (int nt = 0; nt < 8; ++nt) {
        if (nt < NT) {
          int col = nt * 16 + lr;
          float sv = acc[mt][nt][rr] * 0.125f;
          sv = (col <= row) ? sv : -1e30f;
          acc[mt][nt][rr] = sv;
          m = fmaxf(m, sv);
        }
      }
      m = fmaxf(m, __shfl_xor(m, 1));
      m = fmaxf(m, __shfl_xor(m, 2));
      m = fmaxf(m, __shfl_xor(m, 4));
      m = fmaxf(m, __shfl_xor(m, 8));
      float ssum = 0.f;
#pragma unroll
      for (int nt = 0; nt < 8; ++nt) {
        if (nt < NT) {
          float p = __builtin_amdgcn_exp2f((acc[mt][nt][rr] - m) * 1.44269504f);
          acc[mt][nt][rr] = p;
          ssum += p;
        }
      }
      ssum += __shfl_xor(ssum, 1);
      ssum += __shfl_xor(ssum, 2);
      ssum += __shfl_xor(ssum, 4);
      ssum += __shfl_xor(ssum, 8);
      float inv = 1.0f / ssum;
#pragma unroll
      for (int nt = 0; nt < 8; ++nt) {
        if (nt < NT) Ps[row * 136 + nt * 16 + lr] = (bf16_t)(acc[mt][nt][rr] * inv);
      }
    }
  }

  f32x4 oacc[2][4];
#pragma unroll
  for (int mt = 0; mt < 2; ++mt)
#pragma unroll
    for (int dt = 0; dt < 4; ++dt) oacc[mt][dt] = (f32x4){0.f, 0.f, 0.f, 0.f};

  const int KS = w + 1;
#pragma unroll
  for (int ks = 0; ks < 4; ++ks) {
    if (ks < KS) {
      bf16x8 pa0 = *(const bf16x8*)&Ps[(qrow0 + lr) * 136 + ks * 32 + kg * 8];
      bf16x8 pa1 = *(const bf16x8*)&Ps[(qrow0 + 16 + lr) * 136 + ks * 32 + kg * 8];
#pragma unroll
      for (int dt = 0; dt < 4; ++dt) {
        bf16x8 vb = *(const bf16x8*)&Vt[(dt * 16 + lr) * 136 + ks * 32 + kg * 8];
        oacc[0][dt] = mfma16(pa0, vb, oacc[0][dt]);
        oacc[1][dt] = mfma16(pa1, vb, oacc[1][dt]);
      }
    }
  }

#pragma unroll
  for (int mt = 0; mt < 2; ++mt)
#pragma unroll
    for (int dt = 0; dt < 4; ++dt)
#pragma unroll
      for (int rr = 0; rr < 4; ++rr) {
        int t = qrow0 + mt * 16 + kg * 4 + rr;
        obuf[((size_t)b * 128 + t) * 768 + hoff + dt * 16 + lr] = (bf16_t)oacc[mt][dt][rr];
      }
}

// ---------------- launch ----------------
extern "C" void kernel_launch(void* const* d_in, const int* in_sizes, int n_in,
                              void* d_out, int out_size, void* d_ws, size_t ws_size,
                              hipStream_t stream) {
  const float* x = (const float*)d_in[0];       // [128,128,768]
  const float* w_qkv = (const float*)d_in[1];   // [768,2304]
  const float* w_proj = (const float*)d_in[2];  // [768,768]
  float* out = (float*)d_out;
  char* ws = (char*)d_ws;

  bf16_t* xb     = (bf16_t*)(ws);              // 16384*768*2   = 25,165,824
  bf16_t* wqkvt  = (bf16_t*)(ws + 25165824);   // 2304*768*2    =  3,538,944
  bf16_t* wprojt = (bf16_t*)(ws + 28704768);   // 768*768*2     =  1,179,648
  bf16_t* qkv    = (bf16_t*)(ws + 29884416);   // 16384*2304*2  = 75,497,472
  bf16_t* obuf   = (bf16_t*)(ws + 105381888);  // 16384*768*2   = 25,165,824

  prep_kernel<<<dim3(12288 + 2304), dim3(256), 0, stream>>>(x, w_qkv, w_proj, xb, wqkvt, wprojt);
  // GEMM1: BN=128, jobs = 128 bm x 18 bn = 2304; grid 512 (2/CU): q=4, r=256
  gemm_cnt<128, 2, false><<<dim3(512), dim3(256), 0, stream>>>(
      xb, wqkvt, (void*)qkv, 2304, 18, 4, 256);
  attn_kernel<<<dim3(1536), dim3(256), 0, stream>>>(qkv, obuf);
  // GEMM2: BN=64, jobs = 128 bm x 12 bn = 1536; grid 768 (3/CU): q=2, r=0
  gemm_cnt<64, 3, true><<<dim3(768), dim3(256), 0, stream>>>(
      obuf, wprojt, (void*)out, 768, 12, 2, 0);
}

// Round 6
// 162.918 us; speedup vs baseline: 1.0014x; 1.0014x over previous
//
#include <hip/hip_runtime.h>

typedef __bf16 bf16_t;
typedef bf16_t bf16x8 __attribute__((ext_vector_type(8)));
typedef bf16_t bf16x4 __attribute__((ext_vector_type(4)));
typedef float f32x4 __attribute__((ext_vector_type(4)));

__device__ __forceinline__ f32x4 mfma16(bf16x8 a, bf16x8 b, f32x4 c) {
  return __builtin_amdgcn_mfma_f32_16x16x32_bf16(a, b, c, 0, 0, 0);
}

__device__ __forceinline__ void gload16(const bf16_t* g, bf16_t* l) {
  __builtin_amdgcn_global_load_lds(
      (const __attribute__((address_space(1))) void*)g,
      (__attribute__((address_space(3))) void*)l, 16, 0, 0);
}

// ------- merged prep: x f32->bf16 convert + both weight transposes -------
__global__ void prep_kernel(const float* __restrict__ x, const float* __restrict__ wq,
                            const float* __restrict__ wp, bf16_t* __restrict__ xb,
                            bf16_t* __restrict__ wqt, bf16_t* __restrict__ wpt) {
  __shared__ bf16_t tile[32][33];
  const int bid = blockIdx.x;
  if (bid < 12288) {
    int i = bid * 256 + threadIdx.x;
    float4 v = ((const float4*)x)[i];
    bf16x4 o;
    o[0] = (bf16_t)v.x; o[1] = (bf16_t)v.y; o[2] = (bf16_t)v.z; o[3] = (bf16_t)v.w;
    *(bf16x4*)&xb[(size_t)i * 4] = o;
    return;
  }
  const int t = bid - 12288;
  const int ty = t / 96, txb = t % 96;
  const float* in;
  bf16_t* out;
  int N, n0;
  if (txb < 72) { in = wq; out = wqt; N = 2304; n0 = txb * 32; }
  else          { in = wp; out = wpt; N = 768;  n0 = (txb - 72) * 32; }
  const int k0 = ty * 32;
  const int tx = threadIdx.x & 31, tyy = threadIdx.x >> 5;
#pragma unroll
  for (int ph = 0; ph < 4; ++ph) {
    int k = tyy + ph * 8;
    tile[k][tx] = (bf16_t)in[(size_t)(k0 + k) * N + n0 + tx];
  }
  __syncthreads();
#pragma unroll
  for (int ph = 0; ph < 4; ++ph) {
    int n = tyy + ph * 8;
    out[(size_t)(n0 + n) * 768 + k0 + tx] = tile[tx][n];
  }
}

// ------- persistent 128xBN bf16 GEMM, BK=32, round-3 sync, high occupancy -------
// C = A[M][768] * Bt[N][768]^T. 4 waves (2x2). LDS dbuf = (128+BN)*32*2*2 bytes:
// BN=128 -> 32 KiB (3 blocks/CU), BN=64 -> 24 KiB (6 blocks/CU). Per K-step:
//   stage(kt+1 | next job tile0) -> compute(kt) -> __syncthreads()
// Swizzle for 64B rows: chunk p ^ ((row>>1)&3) -> 2 lanes/bank (free).
template <int BN, int MINW, bool F32OUT>
__global__ __launch_bounds__(256, MINW) void gemm_p32(
    const bf16_t* __restrict__ A, const bf16_t* __restrict__ Bt,
    void* __restrict__ Cout, int N, int nbn, int q, int r) {
  constexpr int K = 768;
  constexpr int NKT = 24;       // K / 32
  constexpr int NQ = BN / 32;   // B n-quadrants per wave
  __shared__ bf16_t As[2][128 * 32];
  __shared__ bf16_t Bs[2][BN * 32];
  const int tid = threadIdx.x;
  const int lane = tid & 63;
  const int w = tid >> 6;
  const int wm = w >> 1, wn = w & 1;
  const int lr = lane & 15, kg = lane >> 4;

  // XCD-chunked remap: consecutive jobs (same bm / A panel) stay on one XCD
  const int G = gridDim.x;
  const int bid = blockIdx.x;
  const int lb = (bid & 7) * (G >> 3) + (bid >> 3);
  int nj, start;
  if (lb < r) { nj = q + 1; start = lb * (q + 1); }
  else        { nj = q;     start = r * (q + 1) + (lb - r) * q; }

  auto stage = [&](int buf, const bf16_t* Aj, const bf16_t* Bj, int k0) {
#pragma unroll
    for (int it = 0; it < 2; ++it) {
      int c = it * 256 + tid;
      int rr = c >> 2, p = c & 3;
      gload16(Aj + (size_t)rr * K + (k0 + ((p ^ ((rr >> 1) & 3)) << 3)),
              &As[buf][c * 8]);
    }
#pragma unroll
    for (int it = 0; it < BN / 64; ++it) {
      int c = it * 256 + tid;
      int rr = c >> 2, p = c & 3;
      gload16(Bj + (size_t)rr * K + (k0 + ((p ^ ((rr >> 1) & 3)) << 3)),
              &Bs[buf][c * 8]);
    }
  };

  int job = start;
  int bm = job / nbn, bn = job - bm * nbn;
  const bf16_t* Aj = A + (size_t)bm * (128 * K);
  const bf16_t* Bj = Bt + (size_t)bn * (BN * K);
  stage(0, Aj, Bj, 0);
  __syncthreads();
  int buf = 0;

  const int ph = kg ^ ((lr >> 1) & 3);  // swizzled 8-elem chunk for this lane

  for (int j = 0; j < nj; ++j) {
    f32x4 acc[4][NQ];
#pragma unroll
    for (int i = 0; i < 4; ++i)
#pragma unroll
      for (int n = 0; n < NQ; ++n) acc[i][n] = (f32x4){0.f, 0.f, 0.f, 0.f};

    int nbm = 0, nbnx = 0;
    const bf16_t *nAj = nullptr, *nBj = nullptr;
    if (j + 1 < nj) {
      int njob = job + 1;
      nbm = njob / nbn; nbnx = njob - nbm * nbn;
      nAj = A + (size_t)nbm * (128 * K);
      nBj = Bt + (size_t)nbnx * (BN * K);
    }

    for (int kt = 0; kt < NKT; ++kt) {
      if (kt + 1 < NKT)     stage(buf ^ 1, Aj, Bj, (kt + 1) << 5);
      else if (j + 1 < nj)  stage(buf ^ 1, nAj, nBj, 0);

      bf16x8 af[4], bfv[NQ];
#pragma unroll
      for (int mq = 0; mq < 4; ++mq) {
        int rr = wm * 64 + mq * 16 + lr;
        af[mq] = *(const bf16x8*)&As[buf][(rr << 5) + (ph << 3)];
      }
#pragma unroll
      for (int nq = 0; nq < NQ; ++nq) {
        int rr = wn * (BN / 2) + nq * 16 + lr;
        bfv[nq] = *(const bf16x8*)&Bs[buf][(rr << 5) + (ph << 3)];
      }
#pragma unroll
      for (int mq = 0; mq < 4; ++mq)
#pragma unroll
        for (int nq = 0; nq < NQ; ++nq)
          acc[mq][nq] = mfma16(af[mq], bfv[nq], acc[mq][nq]);

      __syncthreads();
      buf ^= 1;
    }

    // epilogue
    const int row0 = bm * 128 + wm * 64 + kg * 4;
    const int col0 = bn * BN + wn * (BN / 2) + lr;
#pragma unroll
    for (int mq = 0; mq < 4; ++mq)
#pragma unroll
      for (int nq = 0; nq < NQ; ++nq)
#pragma unroll
        for (int rr = 0; rr < 4; ++rr) {
          size_t idx = (size_t)(row0 + mq * 16 + rr) * N + (col0 + nq * 16);
          if constexpr (F32OUT)
            ((float*)Cout)[idx] = acc[mq][nq][rr];
          else
            ((bf16_t*)Cout)[idx] = (bf16_t)acc[mq][nq][rr];
        }

    job++; bm = nbm; bn = nbnx; Aj = nAj; Bj = nBj;
  }
}

// ---------------- causal attention: one block per (b,h) ----------------
#define ATT_H 12
__global__ __launch_bounds__(256, 2) void attn_kernel(const bf16_t* __restrict__ qkv,
                                                      bf16_t* __restrict__ obuf) {
  __shared__ bf16_t Ks[128 * 72];
  __shared__ bf16_t Vt[64 * 136];
  __shared__ bf16_t Ps[128 * 136];
  const int tid = threadIdx.x, lane = tid & 63, w = tid >> 6;
  const int lr = lane & 15, kg = lane >> 4;
  const int bh = blockIdx.x;
  const int b = bh / ATT_H, h = bh % ATT_H;
  const size_t base = (size_t)b * 128 * 2304;
  const int hoff = h * 64;

#pragma unroll
  for (int it = 0; it < 4; ++it) {
    int idx = it * 256 + tid;
    int r = idx >> 3, slot = idx & 7;
    bf16x8 v = *(const bf16x8*)&qkv[base + (size_t)r * 2304 + 768 + hoff + slot * 8];
    *(bf16x8*)&Ks[r * 72 + slot * 8] = v;
  }
#pragma unroll 4
  for (int it = 0; it < 32; ++it) {
    int idx = it * 256 + tid;
    int t = idx >> 6, d = idx & 63;
    Vt[d * 136 + t] = qkv[base + (size_t)t * 2304 + 1536 + hoff + d];
  }
  const int qrow0 = w * 32;
  bf16x8 qf[2][2];
#pragma unroll
  for (int mt = 0; mt < 2; ++mt)
#pragma unroll
    for (int kk = 0; kk < 2; ++kk)
      qf[mt][kk] = *(const bf16x8*)&qkv[base + (size_t)(qrow0 + mt * 16 + lr) * 2304 + hoff +
                                        kk * 32 + kg * 8];
  __syncthreads();

  const int NT = 2 * w + 2;
  f32x4 acc[2][8];
#pragma unroll
  for (int mt = 0; mt < 2; ++mt)
#pragma unroll
    for (int nt = 0; nt < 8; ++nt) acc[mt][nt] = (f32x4){0.f, 0.f, 0.f, 0.f};

#pragma unroll
  for (int nt = 0; nt < 8; ++nt) {
    if (nt < NT) {
#pragma unroll
      for (int kk = 0; kk < 2; ++kk) {
        bf16x8 kf = *(const bf16x8*)&Ks[(nt * 16 + lr) * 72 + kk * 32 + kg * 8];
        acc[0][nt] = mfma16(qf[0][kk], kf, acc[0][nt]);
        acc[1][nt] = mfma16(qf[1][kk], kf, acc[1][nt]);
      }
    }
  }

#pragma unroll
  for (int mt = 0; mt < 2; ++mt) {
#pragma unroll
    for (int rr = 0; rr < 4; ++rr) {
      const int row = qrow0 + mt * 16 + kg * 4 + rr;
      float m = -1e30f;
#pragma unroll
      for (int nt = 0; nt < 8; ++nt) {
        if (nt < NT) {
          int col = nt * 16 + lr;
          float sv = acc[mt][nt][rr] * 0.125f;
          sv = (col <= row) ? sv : -1e30f;
          acc[mt][nt][rr] = sv;
          m = fmaxf(m, sv);
        }
      }
      m = fmaxf(m, __shfl_xor(m, 1));
      m = fmaxf(m, __shfl_xor(m, 2));
      m = fmaxf(m, __shfl_xor(m, 4));
      m = fmaxf(m, __shfl_xor(m, 8));
      float ssum = 0.f;
#pragma unroll
      for (int nt = 0; nt < 8; ++nt) {
        if (nt < NT) {
          float p = __builtin_amdgcn_exp2f((acc[mt][nt][rr] - m) * 1.44269504f);
          acc[mt][nt][rr] = p;
          ssum += p;
        }
      }
      ssum += __shfl_xor(ssum, 1);
      ssum += __shfl_xor(ssum, 2);
      ssum += __shfl_xor(ssum, 4);
      ssum += __shfl_xor(ssum, 8);
      float inv = 1.0f / ssum;
#pragma unroll
      for (int nt = 0; nt < 8; ++nt) {
        if (nt < NT) Ps[row * 136 + nt * 16 + lr] = (bf16_t)(acc[mt][nt][rr] * inv);
      }
    }
  }

  f32x4 oacc[2][4];
#pragma unroll
  for (int mt = 0; mt < 2; ++mt)
#pragma unroll
    for (int dt = 0; dt < 4; ++dt) oacc[mt][dt] = (f32x4){0.f, 0.f, 0.f, 0.f};

  const int KS = w + 1;
#pragma unroll
  for (int ks = 0; ks < 4; ++ks) {
    if (ks < KS) {
      bf16x8 pa0 = *(const bf16x8*)&Ps[(qrow0 + lr) * 136 + ks * 32 + kg * 8];
      bf16x8 pa1 = *(const bf16x8*)&Ps[(qrow0 + 16 + lr) * 136 + ks * 32 + kg * 8];
#pragma unroll
      for (int dt = 0; dt < 4; ++dt) {
        bf16x8 vb = *(const bf16x8*)&Vt[(dt * 16 + lr) * 136 + ks * 32 + kg * 8];
        oacc[0][dt] = mfma16(pa0, vb, oacc[0][dt]);
        oacc[1][dt] = mfma16(pa1, vb, oacc[1][dt]);
      }
    }
  }

#pragma unroll
  for (int mt = 0; mt < 2; ++mt)
#pragma unroll
    for (int dt = 0; dt < 4; ++dt)
#pragma unroll
      for (int rr = 0; rr < 4; ++rr) {
        int t = qrow0 + mt * 16 + kg * 4 + rr;
        obuf[((size_t)b * 128 + t) * 768 + hoff + dt * 16 + lr] = (bf16_t)oacc[mt][dt][rr];
      }
}

// ---------------- launch ----------------
extern "C" void kernel_launch(void* const* d_in, const int* in_sizes, int n_in,
                              void* d_out, int out_size, void* d_ws, size_t ws_size,
                              hipStream_t stream) {
  const float* x = (const float*)d_in[0];       // [128,128,768]
  const float* w_qkv = (const float*)d_in[1];   // [768,2304]
  const float* w_proj = (const float*)d_in[2];  // [768,768]
  float* out = (float*)d_out;
  char* ws = (char*)d_ws;

  bf16_t* xb     = (bf16_t*)(ws);              // 16384*768*2   = 25,165,824
  bf16_t* wqkvt  = (bf16_t*)(ws + 25165824);   // 2304*768*2    =  3,538,944
  bf16_t* wprojt = (bf16_t*)(ws + 28704768);   // 768*768*2     =  1,179,648
  bf16_t* qkv    = (bf16_t*)(ws + 29884416);   // 16384*2304*2  = 75,497,472
  bf16_t* obuf   = (bf16_t*)(ws + 105381888);  // 16384*768*2   = 25,165,824

  prep_kernel<<<dim3(12288 + 2304), dim3(256), 0, stream>>>(x, w_qkv, w_proj, xb, wqkvt, wprojt);
  // GEMM1: BN=128, 32 KiB LDS -> 3 blocks/CU; jobs = 128x18 = 2304; grid 768, 3 each
  gemm_p32<128, 3, false><<<dim3(768), dim3(256), 0, stream>>>(
      xb, wqkvt, (void*)qkv, 2304, 18, 3, 0);
  attn_kernel<<<dim3(1536), dim3(256), 0, stream>>>(qkv, obuf);
  // GEMM2: BN=64, 24 KiB LDS -> 6 blocks/CU; jobs = 128x12 = 1536; grid 1536, 1 each
  gemm_p32<64, 6, true><<<dim3(1536), dim3(256), 0, stream>>>(
      obuf, wprojt, (void*)out, 768, 12, 1, 0);
}

// Round 7
// 159.352 us; speedup vs baseline: 1.0238x; 1.0224x over previous
//
#include <hip/hip_runtime.h>

typedef __bf16 bf16_t;
typedef bf16_t bf16x8 __attribute__((ext_vector_type(8)));
typedef bf16_t bf16x4 __attribute__((ext_vector_type(4)));
typedef float f32x4 __attribute__((ext_vector_type(4)));

__device__ __forceinline__ f32x4 mfma16(bf16x8 a, bf16x8 b, f32x4 c) {
  return __builtin_amdgcn_mfma_f32_16x16x32_bf16(a, b, c, 0, 0, 0);
}

__device__ __forceinline__ void gload16(const bf16_t* g, bf16_t* l) {
  __builtin_amdgcn_global_load_lds(
      (const __attribute__((address_space(1))) void*)g,
      (__attribute__((address_space(3))) void*)l, 16, 0, 0);
}

// ------- prep: weight transposes only: [K][N] f32 -> [N][768] bf16 -------
__global__ void prepw_kernel(const float* __restrict__ wq, const float* __restrict__ wp,
                             bf16_t* __restrict__ wqt, bf16_t* __restrict__ wpt) {
  __shared__ bf16_t tile[32][33];
  const int t = blockIdx.x;
  const int ty = t / 96, txb = t % 96;
  const float* in;
  bf16_t* out;
  int N, n0;
  if (txb < 72) { in = wq; out = wqt; N = 2304; n0 = txb * 32; }
  else          { in = wp; out = wpt; N = 768;  n0 = (txb - 72) * 32; }
  const int k0 = ty * 32;
  const int tx = threadIdx.x & 31, tyy = threadIdx.x >> 5;
#pragma unroll
  for (int ph = 0; ph < 4; ++ph) {
    int k = tyy + ph * 8;
    tile[k][tx] = (bf16_t)in[(size_t)(k0 + k) * N + n0 + tx];
  }
  __syncthreads();
#pragma unroll
  for (int ph = 0; ph < 4; ++ph) {
    int n = tyy + ph * 8;
    out[(size_t)(n0 + n) * 768 + k0 + tx] = tile[tx][n];
  }
}

// ------- GEMM1 with fused f32->bf16 A-staging (T14 issue-early/write-late) -------
// C[16384][2304] = cvt(X[16384][768]) * Wt[2304][768]^T. BK=32, BN=128, 4 waves.
// Per K-step: loadA_regs(next f32) ; gloadB(next) ; compute(cur) ;
//             cvt+ds_write A(next) ; __syncthreads().
// Persistent: grid 768, 3 jobs/block (same bm), XCD-chunked remap.
__global__ __launch_bounds__(256, 3) void gemm1_fused(
    const float* __restrict__ X, const bf16_t* __restrict__ Bt,
    bf16_t* __restrict__ Cout) {
  constexpr int K = 768, NKT = 24, NBN = 18, JPB = 3;
  __shared__ bf16_t As[2][128 * 32];
  __shared__ bf16_t Bs[2][128 * 32];
  const int tid = threadIdx.x;
  const int lane = tid & 63;
  const int w = tid >> 6;
  const int wm = w >> 1, wn = w & 1;
  const int lr = lane & 15, kg = lane >> 4;

  const int G = gridDim.x;
  const int bid = blockIdx.x;
  const int lb = (bid & 7) * (G >> 3) + (bid >> 3);
  const int start = lb * JPB;
  const int bm = start / NBN;              // constant per block
  const int bn0 = start - bm * NBN;
  const float* Xj = X + (size_t)bm * (128 * K);

  // A reg-stage: 2 b128-writes/thread, each from 2 float4 loads
  const int cA0 = tid, cA1 = 256 + tid;
  const int rA0 = cA0 >> 2, pA0 = cA0 & 3;
  const int rA1 = cA1 >> 2, pA1 = cA1 & 3;
  const int sA0 = (pA0 ^ ((rA0 >> 1) & 3)) << 3;  // swizzled source chunk offset
  const int sA1 = (pA1 ^ ((rA1 >> 1) & 3)) << 3;

  float4 lv0a, lv0b, lv1a, lv1b;
  auto loadA = [&](int k0) {
    lv0a = *(const float4*)&Xj[(size_t)rA0 * K + k0 + sA0];
    lv0b = *(const float4*)&Xj[(size_t)rA0 * K + k0 + sA0 + 4];
    lv1a = *(const float4*)&Xj[(size_t)rA1 * K + k0 + sA1];
    lv1b = *(const float4*)&Xj[(size_t)rA1 * K + k0 + sA1 + 4];
  };
  auto writeA = [&](int buf) {
    bf16x8 o0, o1;
    o0[0] = (bf16_t)lv0a.x; o0[1] = (bf16_t)lv0a.y; o0[2] = (bf16_t)lv0a.z; o0[3] = (bf16_t)lv0a.w;
    o0[4] = (bf16_t)lv0b.x; o0[5] = (bf16_t)lv0b.y; o0[6] = (bf16_t)lv0b.z; o0[7] = (bf16_t)lv0b.w;
    o1[0] = (bf16_t)lv1a.x; o1[1] = (bf16_t)lv1a.y; o1[2] = (bf16_t)lv1a.z; o1[3] = (bf16_t)lv1a.w;
    o1[4] = (bf16_t)lv1b.x; o1[5] = (bf16_t)lv1b.y; o1[6] = (bf16_t)lv1b.z; o1[7] = (bf16_t)lv1b.w;
    *(bf16x8*)&As[buf][cA0 * 8] = o0;
    *(bf16x8*)&As[buf][cA1 * 8] = o1;
  };
  auto gloadB = [&](int buf, const bf16_t* Bj, int k0) {
#pragma unroll
    for (int it = 0; it < 2; ++it) {
      int c = it * 256 + tid;
      int rr = c >> 2, p = c & 3;
      gload16(Bj + (size_t)rr * K + (k0 + ((p ^ ((rr >> 1) & 3)) << 3)), &Bs[buf][c * 8]);
    }
  };

  const int ph = kg ^ ((lr >> 1) & 3);

  // prologue: stage step 0
  const bf16_t* Bj = Bt + (size_t)bn0 * (128 * K);
  loadA(0);
  gloadB(0, Bj, 0);
  writeA(0);
  __syncthreads();
  int buf = 0;

  for (int j = 0; j < JPB; ++j) {
    f32x4 acc[4][4];
#pragma unroll
    for (int i = 0; i < 4; ++i)
#pragma unroll
      for (int n = 0; n < 4; ++n) acc[i][n] = (f32x4){0.f, 0.f, 0.f, 0.f};

    const int bn = bn0 + j;
    const bf16_t* BjN = Bt + (size_t)(bn + 1) * (128 * K);  // next job's B

    for (int kt = 0; kt < NKT; ++kt) {
      const bool haveNext = (kt + 1 < NKT) || (j + 1 < JPB);
      const int nk0 = (kt + 1 < NKT) ? ((kt + 1) << 5) : 0;
      const bf16_t* nBj = (kt + 1 < NKT) ? Bj : BjN;
      if (haveNext) {
        loadA(nk0);                // issue f32 loads early
        gloadB(buf ^ 1, nBj, nk0); // fire-and-forget direct-to-LDS
      }
      // compute current tile
      bf16x8 af[4], bfv[4];
#pragma unroll
      for (int mq = 0; mq < 4; ++mq) {
        int rr = wm * 64 + mq * 16 + lr;
        af[mq] = *(const bf16x8*)&As[buf][(rr << 5) + (ph << 3)];
      }
#pragma unroll
      for (int nq = 0; nq < 4; ++nq) {
        int rr = wn * 64 + nq * 16 + lr;
        bfv[nq] = *(const bf16x8*)&Bs[buf][(rr << 5) + (ph << 3)];
      }
#pragma unroll
      for (int mq = 0; mq < 4; ++mq)
#pragma unroll
        for (int nq = 0; nq < 4; ++nq)
          acc[mq][nq] = mfma16(af[mq], bfv[nq], acc[mq][nq]);

      if (haveNext) writeA(buf ^ 1);  // cvt+LDS write late (loads drained here)
      __syncthreads();
      buf ^= 1;
    }

    const int row0 = bm * 128 + wm * 64 + kg * 4;
    const int col0 = bn * 128 + wn * 64 + lr;
#pragma unroll
    for (int mq = 0; mq < 4; ++mq)
#pragma unroll
      for (int nq = 0; nq < 4; ++nq)
#pragma unroll
        for (int rr = 0; rr < 4; ++rr)
          Cout[(size_t)(row0 + mq * 16 + rr) * 2304 + (col0 + nq * 16)] =
              (bf16_t)acc[mq][nq][rr];

    Bj = BjN;
  }
}

// ------- GEMM2: 128x128, BK=32, grid 768 = 1 round at 3 blocks/CU -------
__global__ __launch_bounds__(256, 3) void gemm2_kernel(
    const bf16_t* __restrict__ A, const bf16_t* __restrict__ Bt,
    float* __restrict__ Cout) {
  constexpr int K = 768, NKT = 24, NBN = 6;
  __shared__ bf16_t As[2][128 * 32];
  __shared__ bf16_t Bs[2][128 * 32];
  const int tid = threadIdx.x;
  const int lane = tid & 63;
  const int w = tid >> 6;
  const int wm = w >> 1, wn = w & 1;
  const int lr = lane & 15, kg = lane >> 4;

  const int G = gridDim.x;
  const int bid = blockIdx.x;
  const int lb = (bid & 7) * (G >> 3) + (bid >> 3);
  const int bm = lb / NBN, bn = lb - bm * NBN;
  const bf16_t* Aj = A + (size_t)bm * (128 * K);
  const bf16_t* Bj = Bt + (size_t)bn * (128 * K);

  auto stage = [&](int buf, int k0) {
#pragma unroll
    for (int it = 0; it < 2; ++it) {
      int c = it * 256 + tid;
      int rr = c >> 2, p = c & 3;
      int so = k0 + ((p ^ ((rr >> 1) & 3)) << 3);
      gload16(Aj + (size_t)rr * K + so, &As[buf][c * 8]);
      gload16(Bj + (size_t)rr * K + so, &Bs[buf][c * 8]);
    }
  };

  stage(0, 0);
  __syncthreads();
  int buf = 0;

  f32x4 acc[4][4];
#pragma unroll
  for (int i = 0; i < 4; ++i)
#pragma unroll
    for (int n = 0; n < 4; ++n) acc[i][n] = (f32x4){0.f, 0.f, 0.f, 0.f};

  const int ph = kg ^ ((lr >> 1) & 3);

  for (int kt = 0; kt < NKT; ++kt) {
    if (kt + 1 < NKT) stage(buf ^ 1, (kt + 1) << 5);
    bf16x8 af[4], bfv[4];
#pragma unroll
    for (int mq = 0; mq < 4; ++mq) {
      int rr = wm * 64 + mq * 16 + lr;
      af[mq] = *(const bf16x8*)&As[buf][(rr << 5) + (ph << 3)];
    }
#pragma unroll
    for (int nq = 0; nq < 4; ++nq) {
      int rr = wn * 64 + nq * 16 + lr;
      bfv[nq] = *(const bf16x8*)&Bs[buf][(rr << 5) + (ph << 3)];
    }
#pragma unroll
    for (int mq = 0; mq < 4; ++mq)
#pragma unroll
      for (int nq = 0; nq < 4; ++nq)
        acc[mq][nq] = mfma16(af[mq], bfv[nq], acc[mq][nq]);
    __syncthreads();
    buf ^= 1;
  }

  const int row0 = bm * 128 + wm * 64 + kg * 4;
  const int col0 = bn * 128 + wn * 64 + lr;
#pragma unroll
  for (int mq = 0; mq < 4; ++mq)
#pragma unroll
    for (int nq = 0; nq < 4; ++nq)
#pragma unroll
      for (int rr = 0; rr < 4; ++rr)
        Cout[(size_t)(row0 + mq * 16 + rr) * 768 + (col0 + nq * 16)] = acc[mq][nq][rr];
}

// ---------------- causal attention: one block per (b,h) ----------------
#define ATT_H 12
__global__ __launch_bounds__(256, 2) void attn_kernel(const bf16_t* __restrict__ qkv,
                                                      bf16_t* __restrict__ obuf) {
  __shared__ bf16_t Ks[128 * 72];
  __shared__ bf16_t Vt[64 * 136];
  __shared__ bf16_t Ps[128 * 136];
  const int tid = threadIdx.x, lane = tid & 63, w = tid >> 6;
  const int lr = lane & 15, kg = lane >> 4;
  const int bh = blockIdx.x;
  const int b = bh / ATT_H, h = bh % ATT_H;
  const size_t base = (size_t)b * 128 * 2304;
  const int hoff = h * 64;

#pragma unroll
  for (int it = 0; it < 4; ++it) {
    int idx = it * 256 + tid;
    int r = idx >> 3, slot = idx & 7;
    bf16x8 v = *(const bf16x8*)&qkv[base + (size_t)r * 2304 + 768 + hoff + slot * 8];
    *(bf16x8*)&Ks[r * 72 + slot * 8] = v;
  }
#pragma unroll 4
  for (int it = 0; it < 32; ++it) {
    int idx = it * 256 + tid;
    int t = idx >> 6, d = idx & 63;
    Vt[d * 136 + t] = qkv[base + (size_t)t * 2304 + 1536 + hoff + d];
  }
  const int qrow0 = w * 32;
  bf16x8 qf[2][2];
#pragma unroll
  for (int mt = 0; mt < 2; ++mt)
#pragma unroll
    for (int kk = 0; kk < 2; ++kk)
      qf[mt][kk] = *(const bf16x8*)&qkv[base + (size_t)(qrow0 + mt * 16 + lr) * 2304 + hoff +
                                        kk * 32 + kg * 8];
  __syncthreads();

  const int NT = 2 * w + 2;
  f32x4 acc[2][8];
#pragma unroll
  for (int mt = 0; mt < 2; ++mt)
#pragma unroll
    for (int nt = 0; nt < 8; ++nt) acc[mt][nt] = (f32x4){0.f, 0.f, 0.f, 0.f};

#pragma unroll
  for (int nt = 0; nt < 8; ++nt) {
    if (nt < NT) {
#pragma unroll
      for (int kk = 0; kk < 2; ++kk) {
        bf16x8 kf = *(const bf16x8*)&Ks[(nt * 16 + lr) * 72 + kk * 32 + kg * 8];
        acc[0][nt] = mfma16(qf[0][kk], kf, acc[0][nt]);
        acc[1][nt] = mfma16(qf[1][kk], kf, acc[1][nt]);
      }
    }
  }

#pragma unroll
  for (int mt = 0; mt < 2; ++mt) {
#pragma unroll
    for (int rr = 0; rr < 4; ++rr) {
      const int row = qrow0 + mt * 16 + kg * 4 + rr;
      float m = -1e30f;
#pragma unroll
      for (int nt = 0; nt < 8; ++nt) {
        if (nt < NT) {
          int col = nt * 16 + lr;
          float sv = acc[mt][nt][rr] * 0.125f;
          sv = (col <= row) ? sv : -1e30f;
          acc[mt][nt][rr] = sv;
          m = fmaxf(m, sv);
        }
      }
      m = fmaxf(m, __shfl_xor(m, 1));
      m = fmaxf(m, __shfl_xor(m, 2));
      m = fmaxf(m, __shfl_xor(m, 4));
      m = fmaxf(m, __shfl_xor(m, 8));
      float ssum = 0.f;
#pragma unroll
      for (int nt = 0; nt < 8; ++nt) {
        if (nt < NT) {
          float p = __builtin_amdgcn_exp2f((acc[mt][nt][rr] - m) * 1.44269504f);
          acc[mt][nt][rr] = p;
          ssum += p;
        }
      }
      ssum += __shfl_xor(ssum, 1);
      ssum += __shfl_xor(ssum, 2);
      ssum += __shfl_xor(ssum, 4);
      ssum += __shfl_xor(ssum, 8);
      float inv = 1.0f / ssum;
#pragma unroll
      for (int nt = 0; nt < 8; ++nt) {
        if (nt < NT) Ps[row * 136 + nt * 16 + lr] = (bf16_t)(acc[mt][nt][rr] * inv);
      }
    }
  }

  f32x4 oacc[2][4];
#pragma unroll
  for (int mt = 0; mt < 2; ++mt)
#pragma unroll
    for (int dt = 0; dt < 4; ++dt) oacc[mt][dt] = (f32x4){0.f, 0.f, 0.f, 0.f};

  const int KS = w + 1;
#pragma unroll
  for (int ks = 0; ks < 4; ++ks) {
    if (ks < KS) {
      bf16x8 pa0 = *(const bf16x8*)&Ps[(qrow0 + lr) * 136 + ks * 32 + kg * 8];
      bf16x8 pa1 = *(const bf16x8*)&Ps[(qrow0 + 16 + lr) * 136 + ks * 32 + kg * 8];
#pragma unroll
      for (int dt = 0; dt < 4; ++dt) {
        bf16x8 vb = *(const bf16x8*)&Vt[(dt * 16 + lr) * 136 + ks * 32 + kg * 8];
        oacc[0][dt] = mfma16(pa0, vb, oacc[0][dt]);
        oacc[1][dt] = mfma16(pa1, vb, oacc[1][dt]);
      }
    }
  }

#pragma unroll
  for (int mt = 0; mt < 2; ++mt)
#pragma unroll
    for (int dt = 0; dt < 4; ++dt)
#pragma unroll
      for (int rr = 0; rr < 4; ++rr) {
        int t = qrow0 + mt * 16 + kg * 4 + rr;
        obuf[((size_t)b * 128 + t) * 768 + hoff + dt * 16 + lr] = (bf16_t)oacc[mt][dt][rr];
      }
}

// ---------------- launch ----------------
extern "C" void kernel_launch(void* const* d_in, const int* in_sizes, int n_in,
                              void* d_out, int out_size, void* d_ws, size_t ws_size,
                              hipStream_t stream) {
  const float* x = (const float*)d_in[0];       // [128,128,768]
  const float* w_qkv = (const float*)d_in[1];   // [768,2304]
  const float* w_proj = (const float*)d_in[2];  // [768,768]
  float* out = (float*)d_out;
  char* ws = (char*)d_ws;

  bf16_t* wqkvt  = (bf16_t*)(ws);              // 2304*768*2    =  3,538,944
  bf16_t* wprojt = (bf16_t*)(ws + 3538944);    // 768*768*2     =  1,179,648
  bf16_t* qkv    = (bf16_t*)(ws + 4718592);    // 16384*2304*2  = 75,497,472
  bf16_t* obuf   = (bf16_t*)(ws + 80216064);   // 16384*768*2   = 25,165,824

  prepw_kernel<<<dim3(2304), dim3(256), 0, stream>>>(w_qkv, w_proj, wqkvt, wprojt);
  // GEMM1 fused: jobs = 128 bm x 18 bn = 2304 = 768 blocks x 3 (same bm per block)
  gemm1_fused<<<dim3(768), dim3(256), 0, stream>>>(x, wqkvt, qkv);
  attn_kernel<<<dim3(1536), dim3(256), 0, stream>>>(qkv, obuf);
  // GEMM2: jobs = 128 bm x 6 bn = 768 blocks, 1 each, 3 blocks/CU = 1 round
  gemm2_kernel<<<dim3(768), dim3(256), 0, stream>>>(obuf, wprojt, out);
}